// Round 5
// baseline (6022.786 us; speedup 1.0000x reference)
//
#include <hip/hip_runtime.h>

typedef __attribute__((ext_vector_type(8))) short short8;
typedef __attribute__((ext_vector_type(4))) float f32x4;

#define NB 64
#define NS 512
#define NF 128
#define NH 512
#define NG 2048   // 4*H
#define NBLK 256
#define TH_SLOT (64 * 512)   // dwords per slot: [64 rows][512 cols]

__device__ __forceinline__ unsigned short f2bf(float f) {
    unsigned int u = __builtin_bit_cast(unsigned int, f);
    u = (u + 0x7fffu + ((u >> 16) & 1u)) >> 16;
    return (unsigned short)u;
}
__device__ __forceinline__ float sigm(float x) { return 1.0f / (1.0f + __expf(-x)); }
__device__ __forceinline__ float tanh_(float x) {
    float e = __expf(2.0f * fabsf(x));
    float r = 1.0f - 2.0f / (e + 1.0f);
    return x < 0.0f ? -r : r;
}

__global__ void cvt_bf16(const float* __restrict__ in, unsigned short* __restrict__ out, int n) {
    int i = blockIdx.x * blockDim.x + threadIdx.x;
    int stride = gridDim.x * blockDim.x;
    for (; i < n; i += stride) out[i] = f2bf(in[i]);
}

// out[n][k] = bf16(in[k][n])   in: [K][N] f32 row-major
__global__ void tr_cvt(const float* __restrict__ in, unsigned short* __restrict__ out, int K, int N) {
    int i = blockIdx.x * blockDim.x + threadIdx.x;
    if (i >= K * N) return;
    int n = i / K, k = i - n * K;
    out[i] = f2bf(in[k * N + n]);
}

// Persistent 2-layer LSTM, layer-pipelined (513 rounds), tagged-word dataflow:
// h is exchanged as 4B words [tag:16|bf16:16] in double-buffered th[2][64][512]
// per layer. No flags, no store drains — consumers poll the data itself
// (probe 1 word per 32-col group, then full load + verify-all). Back-pressure:
// a producer writing step r+1 observed all blocks' tag-r words (it reads all
// columns), so every block has finished reading r-1, the overwrite victim.
__global__ void __launch_bounds__(64, 1) lstm_coop(
    const unsigned short* __restrict__ xbf,
    unsigned* __restrict__ th0,                // [2][64][512] tagged words
    unsigned* __restrict__ th1,
    const unsigned short* __restrict__ whT0,
    const unsigned short* __restrict__ wxT0,
    const unsigned short* __restrict__ whT1,
    const unsigned short* __restrict__ wxT1,
    const float* __restrict__ b0,
    const float* __restrict__ b1,
    float* __restrict__ hlast)
{
    __shared__ unsigned short w0lds[32 * 640];    // 40 KB: [32 gate-cols][512+128]
    __shared__ unsigned short w1lds[32 * 1024];   // 64 KB: [32 gate-cols][512+512]

    const int lane = threadIdx.x;
    const int c16  = lane & 15;
    const int kg   = lane >> 4;
    const int bg   = blockIdx.x >> 6;   // 0..3
    const int ct   = blockIdx.x & 63;   // 0..63

    // ---- stage both weight slices: local row n -> gate q=n>>3, hcol ct*8+(n&7)
    auto loadw = [&](unsigned short* dst, const unsigned short* whT,
                     const unsigned short* wxT, int Kx, int rowB) {
        int cpr = (NH + Kx) >> 3;
        for (int idx = lane; idx < 32 * cpr; idx += 64) {
            int n = idx / cpr, cc = idx - n * cpr;
            int G = (n >> 3) * NH + ct * 8 + (n & 7);
            uint4 v = (cc < 64) ? *(const uint4*)(whT + (size_t)G * NH + cc * 8)
                                : *(const uint4*)(wxT + (size_t)G * Kx + (size_t)(cc - 64) * 8);
            *(uint4*)((char*)dst + n * rowB + ((cc * 16) ^ ((n & 7) << 4))) = v;
        }
    };
    loadw(w0lds, whT0, wxT0, NF, 1280);
    loadw(w1lds, whT1, wxT1, NH, 2048);
    __syncthreads();

    const int hc8 = c16 & 7;
    const float bi0 = b0[0 * NH + ct * 8 + hc8], bf0 = b0[1 * NH + ct * 8 + hc8];
    const float bg0 = b0[2 * NH + ct * 8 + hc8], bo0 = b0[3 * NH + ct * 8 + hc8];
    const float bi1 = b1[0 * NH + ct * 8 + hc8], bf1 = b1[1 * NH + ct * 8 + hc8];
    const float bg1 = b1[2 * NH + ct * 8 + hc8], bo1 = b1[3 * NH + ct * 8 + hc8];

    const int arow = bg * 16 + c16;     // A-fragment row this lane reads
    const size_t aseq = (size_t)arow * NS;
    float cst0[4] = {0.f, 0.f, 0.f, 0.f};
    float cst1[4] = {0.f, 0.f, 0.f, 0.f};

    const char* lA0 = (const char*)w0lds + (size_t)c16 * 1280;
    const char* lB0 = (const char*)w0lds + (size_t)(16 + c16) * 1280;
    const char* lA1 = (const char*)w1lds + (size_t)c16 * 2048;
    const char* lB1 = (const char*)w1lds + (size_t)(16 + c16) * 2048;
    const int swz = (c16 & 7) << 4;

    // Poll a tagged tensor slot until every word this lane needs carries `want`;
    // extract bf16 values into frag[16]. 2 batches of 8 k-groups (VGPR control).
    auto poll_tensor = [&](const unsigned* tslot, unsigned want, short8* frag) {
        const unsigned long long* p0 =
            (const unsigned long long*)(tslot + (size_t)arow * NH) + kg * 4;
        for (int b = 0; b < 2; ++b) {
            // probe word0 of each k-group (1/8 of the traffic) until tags match
            for (;;) {
                unsigned bad = 0;
                #pragma unroll
                for (int j = 0; j < 8; ++j) {
                    unsigned w0 = __hip_atomic_load(
                        (const unsigned*)(p0 + (size_t)(b * 8 + j) * 16),
                        __ATOMIC_RELAXED, __HIP_MEMORY_SCOPE_AGENT);
                    bad |= (w0 >> 16) ^ want;
                }
                if (__ballot(bad != 0) == 0ull) break;
            }
            // full load + verify-all (retry whole batch on any stale word)
            for (;;) {
                unsigned long long d[8][4];
                #pragma unroll
                for (int j = 0; j < 8; ++j)
                    #pragma unroll
                    for (int w = 0; w < 4; ++w)
                        d[j][w] = __hip_atomic_load(
                            p0 + (size_t)(b * 8 + j) * 16 + w,
                            __ATOMIC_RELAXED, __HIP_MEMORY_SCOPE_AGENT);
                unsigned bad = 0;
                #pragma unroll
                for (int j = 0; j < 8; ++j)
                    #pragma unroll
                    for (int w = 0; w < 4; ++w) {
                        unsigned long long x = d[j][w];
                        bad |= (((unsigned)(x >> 16) & 0xFFFFu) ^ want)
                             | ((unsigned)(x >> 48) ^ want);
                    }
                if (__ballot(bad != 0) == 0ull) {
                    #pragma unroll
                    for (int j = 0; j < 8; ++j) {
                        short8 s;
                        #pragma unroll
                        for (int w = 0; w < 4; ++w) {
                            s[2 * w]     = (short)(unsigned short)(d[j][w] & 0xFFFFu);
                            s[2 * w + 1] = (short)(unsigned short)((d[j][w] >> 32) & 0xFFFFu);
                        }
                        frag[b * 8 + j] = s;
                    }
                    break;
                }
            }
        }
        __builtin_amdgcn_sched_barrier(0);
    };

    // epilogue: lane l and l^8 hold {i,f} / {g,o} swapped for same hcol
    auto epilogue = [&](f32x4 acc0, f32x4 acc1, float* cst,
                        float bi, float bf_, float bgt, float bo,
                        unsigned* tslot, unsigned tag, bool wlast) {
        f32x4 s0, s1;
        #pragma unroll
        for (int i = 0; i < 4; ++i) {
            s0[i] = __shfl_xor(acc0[i], 8, 64);
            s1[i] = __shfl_xor(acc1[i], 8, 64);
        }
        const bool lower = (c16 < 8);
        unsigned* tw = tslot + (size_t)(bg * 16 + kg * 4) * NH + ct * 8 + hc8;
        #pragma unroll
        for (int i = 0; i < 4; ++i) {
            float gi = (lower ? acc0[i] : s0[i]) + bi;
            float gf = (lower ? s0[i] : acc0[i]) + bf_;
            float gg = (lower ? acc1[i] : s1[i]) + bgt;
            float go = (lower ? s1[i] : acc1[i]) + bo;
            float c_ = sigm(gf) * cst[i] + sigm(gi) * tanh_(gg);
            cst[i] = c_;
            float hv = sigm(go) * tanh_(c_);
            if (lower) {
                __hip_atomic_store(tw + (size_t)i * NH,
                                   (tag << 16) | (unsigned)f2bf(hv),
                                   __ATOMIC_RELAXED, __HIP_MEMORY_SCOPE_AGENT);
                if (wlast)
                    hlast[(bg * 16 + kg * 4 + i) * NH + ct * 8 + hc8] = hv;
            }
        }
    };

    short8 hfrag[16];   // h0[r-1] values: L0 h-part AND L1 x-part; reused for th1

    for (int r = 0; r <= NS; ++r) {
        f32x4 a0 = {0.f, 0.f, 0.f, 0.f};
        f32x4 a1 = {0.f, 0.f, 0.f, 0.f};
        // ---- L0 x-part first (independent of recurrence)
        if (r < NS) {
            const unsigned short* xp = xbf + (aseq + r) * NF + kg * 8;
            #pragma unroll
            for (int ks = 0; ks < 4; ++ks) {
                short8 a = *(const short8*)(xp + ks * 32);
                int boff = 1024 + ks * 64 + kg * 16;
                a0 = __builtin_amdgcn_mfma_f32_16x16x32_bf16(a, *(const short8*)(lA0 + (boff ^ swz)), a0, 0, 0, 0);
                a1 = __builtin_amdgcn_mfma_f32_16x16x32_bf16(a, *(const short8*)(lB0 + (boff ^ swz)), a1, 0, 0, 0);
            }
        }
        // ---- acquire h0[r-1] (tagged poll; tag = r)
        if (r > 0) poll_tensor(th0 + ((r - 1) & 1) * TH_SLOT, (unsigned)r, hfrag);
        // ---- L0 h-part + epilogue: produces h0[r], tag r+1
        if (r < NS) {
            if (r > 0) {
                #pragma unroll
                for (int ks = 0; ks < 16; ++ks) {
                    int boff = ks * 64 + kg * 16;
                    a0 = __builtin_amdgcn_mfma_f32_16x16x32_bf16(hfrag[ks], *(const short8*)(lA0 + (boff ^ swz)), a0, 0, 0, 0);
                    a1 = __builtin_amdgcn_mfma_f32_16x16x32_bf16(hfrag[ks], *(const short8*)(lB0 + (boff ^ swz)), a1, 0, 0, 0);
                }
            }
            epilogue(a0, a1, cst0, bi0, bf0, bg0, bo0,
                     th0 + (r & 1) * TH_SLOT, (unsigned)(r + 1), false);
        }
        // ---- L1 half: step t1 = r-1; x-part (hfrag, in-reg) hides th1 poll
        if (r > 0) {
            int t1 = r - 1;
            f32x4 c0 = {0.f, 0.f, 0.f, 0.f};
            f32x4 c1 = {0.f, 0.f, 0.f, 0.f};
            #pragma unroll
            for (int ks = 0; ks < 16; ++ks) {
                int boff = 1024 + ks * 64 + kg * 16;
                c0 = __builtin_amdgcn_mfma_f32_16x16x32_bf16(hfrag[ks], *(const short8*)(lA1 + (boff ^ swz)), c0, 0, 0, 0);
                c1 = __builtin_amdgcn_mfma_f32_16x16x32_bf16(hfrag[ks], *(const short8*)(lB1 + (boff ^ swz)), c1, 0, 0, 0);
            }
            if (t1 > 0) {
                poll_tensor(th1 + (r & 1) * TH_SLOT, (unsigned)t1, hfrag);
                #pragma unroll
                for (int ks = 0; ks < 16; ++ks) {
                    int boff = ks * 64 + kg * 16;
                    c0 = __builtin_amdgcn_mfma_f32_16x16x32_bf16(hfrag[ks], *(const short8*)(lA1 + (boff ^ swz)), c0, 0, 0, 0);
                    c1 = __builtin_amdgcn_mfma_f32_16x16x32_bf16(hfrag[ks], *(const short8*)(lB1 + (boff ^ swz)), c1, 0, 0, 0);
                }
            }
            epilogue(c0, c1, cst1, bi1, bf1, bg1, bo1,
                     th1 + (t1 & 1) * TH_SLOT, (unsigned)(t1 + 1), t1 == NS - 1);
        }
    }
}

// one block per batch row; mode 1 = relu, 2 = sigmoid
__global__ void dense(const float* __restrict__ in, const float* __restrict__ W,
                      const float* __restrict__ bias, float* __restrict__ out,
                      int K, int N, int mode) {
    int b = blockIdx.x;
    int j = threadIdx.x;
    extern __shared__ float srow[];
    for (int k = j; k < K; k += blockDim.x) srow[k] = in[b * K + k];
    __syncthreads();
    if (j < N) {
        float acc = bias[j];
        for (int k = 0; k < K; ++k) acc += srow[k] * W[k * N + j];
        if (mode == 1) acc = fmaxf(acc, 0.0f);
        else           acc = 1.0f / (1.0f + __expf(-acc));
        out[b * N + j] = acc;
    }
}

extern "C" void kernel_launch(void* const* d_in, const int* in_sizes, int n_in,
                              void* d_out, int out_size, void* d_ws, size_t ws_size,
                              hipStream_t stream) {
    const float* x    = (const float*)d_in[0];
    const float* Wx0  = (const float*)d_in[1];
    const float* Wh0  = (const float*)d_in[2];
    const float* b0   = (const float*)d_in[3];
    const float* Wx1  = (const float*)d_in[4];
    const float* Wh1  = (const float*)d_in[5];
    const float* b1   = (const float*)d_in[6];
    const float* Wd0  = (const float*)d_in[7];
    const float* bd0  = (const float*)d_in[8];
    const float* Wd1  = (const float*)d_in[9];
    const float* bd1  = (const float*)d_in[10];
    const float* Wout = (const float*)d_in[11];
    const float* bout = (const float*)d_in[12];

    char* ws = (char*)d_ws;
    size_t off = 0;
    auto alloc = [&](size_t bytes) { void* p = ws + off; off += (bytes + 255) & ~255ull; return p; };
    unsigned* th0 = (unsigned*)alloc((size_t)2 * TH_SLOT * 4);
    unsigned* th1 = (unsigned*)alloc((size_t)2 * TH_SLOT * 4);
    unsigned short* xbf  = (unsigned short*)alloc((size_t)NB * NS * NF * 2);
    unsigned short* whT0 = (unsigned short*)alloc((size_t)NG * NH * 2);
    unsigned short* wxT0 = (unsigned short*)alloc((size_t)NG * NF * 2);
    unsigned short* whT1 = (unsigned short*)alloc((size_t)NG * NH * 2);
    unsigned short* wxT1 = (unsigned short*)alloc((size_t)NG * NH * 2);
    float* hlast = (float*)alloc((size_t)NB * NH * 4);
    float* dt0   = (float*)alloc((size_t)NB * 512 * 4);
    float* dt1   = (float*)alloc((size_t)NB * 256 * 4);

    // zero tags EVERY launch: poison-garbage and stale tags from a previous
    // replay must never satisfy a poll.
    hipMemsetAsync(th0, 0, (size_t)4 * TH_SLOT * 4, stream);
    cvt_bf16<<<2048, 256, 0, stream>>>(x, xbf, NB * NS * NF);
    tr_cvt<<<(NG * NF + 255) / 256, 256, 0, stream>>>(Wx0, wxT0, NF, NG);
    tr_cvt<<<(NG * NH + 255) / 256, 256, 0, stream>>>(Wh0, whT0, NH, NG);
    tr_cvt<<<(NG * NH + 255) / 256, 256, 0, stream>>>(Wx1, wxT1, NH, NG);
    tr_cvt<<<(NG * NH + 255) / 256, 256, 0, stream>>>(Wh1, whT1, NH, NG);

    void* args[] = { (void*)&xbf, (void*)&th0, (void*)&th1,
                     (void*)&whT0, (void*)&wxT0, (void*)&whT1, (void*)&wxT1,
                     (void*)&b0, (void*)&b1, (void*)&hlast };
    hipLaunchCooperativeKernel((void*)lstm_coop, dim3(NBLK), dim3(64), args, 0, stream);

    dense<<<NB, 512, 512 * 4, stream>>>(hlast, Wd0, bd0, dt0, 512, 512, 1);
    dense<<<NB, 256, 512 * 4, stream>>>(dt0, Wd1, bd1, dt1, 512, 256, 1);
    dense<<<NB, 128, 256 * 4, stream>>>(dt1, Wout, bout, (float*)d_out, 256, 96, 2);
}

// Round 8
// 5343.341 us; speedup vs baseline: 1.1272x; 1.1272x over previous
//
#include <hip/hip_runtime.h>

typedef __attribute__((ext_vector_type(8))) short short8;
typedef __attribute__((ext_vector_type(4))) float f32x4;
typedef unsigned long long ull;

#define NB 64
#define NS 512
#define NF 128
#define NH 512
#define NG 2048   // 4*H
#define NBLK 256
#define TH_SLOT (64 * 512)   // dwords per slot: [64 rows][512 cols]

__device__ __forceinline__ unsigned short f2bf(float f) {
    unsigned int u = __builtin_bit_cast(unsigned int, f);
    u = (u + 0x7fffu + ((u >> 16) & 1u)) >> 16;
    return (unsigned short)u;
}
__device__ __forceinline__ float sigm(float x) { return 1.0f / (1.0f + __expf(-x)); }
__device__ __forceinline__ float tanh_(float x) {
    float e = __expf(2.0f * fabsf(x));
    float r = 1.0f - 2.0f / (e + 1.0f);
    return x < 0.0f ? -r : r;
}

__device__ __forceinline__ ull ld64(const ull* p) {
    return __hip_atomic_load(p, __ATOMIC_RELAXED, __HIP_MEMORY_SCOPE_AGENT);
}

__global__ void cvt_bf16(const float* __restrict__ in, unsigned short* __restrict__ out, int n) {
    int i = blockIdx.x * blockDim.x + threadIdx.x;
    int stride = gridDim.x * blockDim.x;
    for (; i < n; i += stride) out[i] = f2bf(in[i]);
}

// out[n][k] = bf16(in[k][n])   in: [K][N] f32 row-major
__global__ void tr_cvt(const float* __restrict__ in, unsigned short* __restrict__ out, int K, int N) {
    int i = blockIdx.x * blockDim.x + threadIdx.x;
    if (i >= K * N) return;
    int n = i / K, k = i - n * K;
    out[i] = f2bf(in[k * N + n]);
}

// Persistent 2-layer LSTM, layer-pipelined (513 rounds), tagged-word dataflow
// (R4 structure, which PASSED; poll thinned from 4 dependent fabric phases to
// 2). h exchanged as 4B words [tag:16|bf16:16] in double-buffered
// th[2][64][512] per layer. Poll = full load + tag-verify + retry (no separate
// probe spin: the verify loop IS the spin; steady-state data has ~half-round
// slack so attempt 1 usually succeeds -> ~1 RTT per batch).
// Back-pressure (unchanged from R4): a producer's stores are data-dependent on
// its poll loads, and observing all blocks' tag-r words implies every block
// finished the poll whose slot the new store overwrites.
__global__ void __launch_bounds__(64, 1) lstm_coop(
    const unsigned short* __restrict__ xbf,
    unsigned* __restrict__ th0,                // [2][64][512] tagged words
    unsigned* __restrict__ th1,
    const unsigned short* __restrict__ whT0,
    const unsigned short* __restrict__ wxT0,
    const unsigned short* __restrict__ whT1,
    const unsigned short* __restrict__ wxT1,
    const float* __restrict__ b0,
    const float* __restrict__ b1,
    float* __restrict__ hlast)
{
    __shared__ unsigned short w0lds[32 * 640];    // 40 KB: [32 gate-cols][512+128]
    __shared__ unsigned short w1lds[32 * 1024];   // 64 KB: [32 gate-cols][512+512]

    const int lane = threadIdx.x;
    const int c16  = lane & 15;
    const int kg   = lane >> 4;
    const int bg   = blockIdx.x >> 6;   // 0..3
    const int ct   = blockIdx.x & 63;   // 0..63

    // ---- stage both weight slices: local row n -> gate q=n>>3, hcol ct*8+(n&7)
    auto loadw = [&](unsigned short* dst, const unsigned short* whT,
                     const unsigned short* wxT, int Kx, int rowB) {
        int cpr = (NH + Kx) >> 3;
        for (int idx = lane; idx < 32 * cpr; idx += 64) {
            int n = idx / cpr, cc = idx - n * cpr;
            int G = (n >> 3) * NH + ct * 8 + (n & 7);
            uint4 v = (cc < 64) ? *(const uint4*)(whT + (size_t)G * NH + cc * 8)
                                : *(const uint4*)(wxT + (size_t)G * Kx + (size_t)(cc - 64) * 8);
            *(uint4*)((char*)dst + n * rowB + ((cc * 16) ^ ((n & 7) << 4))) = v;
        }
    };
    loadw(w0lds, whT0, wxT0, NF, 1280);
    loadw(w1lds, whT1, wxT1, NH, 2048);
    __syncthreads();

    const int hc8 = c16 & 7;
    const float bi0 = b0[0 * NH + ct * 8 + hc8], bf0 = b0[1 * NH + ct * 8 + hc8];
    const float bg0 = b0[2 * NH + ct * 8 + hc8], bo0 = b0[3 * NH + ct * 8 + hc8];
    const float bi1 = b1[0 * NH + ct * 8 + hc8], bf1 = b1[1 * NH + ct * 8 + hc8];
    const float bg1 = b1[2 * NH + ct * 8 + hc8], bo1 = b1[3 * NH + ct * 8 + hc8];

    const int arow = bg * 16 + c16;     // A-fragment row this lane reads
    const size_t aseq = (size_t)arow * NS;
    float cst0[4] = {0.f, 0.f, 0.f, 0.f};
    float cst1[4] = {0.f, 0.f, 0.f, 0.f};

    const char* lA0 = (const char*)w0lds + (size_t)c16 * 1280;
    const char* lB0 = (const char*)w0lds + (size_t)(16 + c16) * 1280;
    const char* lA1 = (const char*)w1lds + (size_t)c16 * 2048;
    const char* lB1 = (const char*)w1lds + (size_t)(16 + c16) * 2048;
    const int swz = (c16 & 7) << 4;

    // Poll a tagged tensor slot until every word this lane needs carries `want`;
    // extract bf16 values into frag[16]. 2 batches of 8 k-groups (VGPR control).
    // No probe phase: load+verify+retry only (2 dependent fabric phases total).
    auto poll_tensor = [&](const unsigned* tslot, unsigned want, short8* frag) {
        const ull* p0 = (const ull*)(tslot + (size_t)arow * NH) + kg * 4;
        #pragma unroll
        for (int b = 0; b < 2; ++b) {
            for (;;) {
                ull d[8][4];
                #pragma unroll
                for (int j = 0; j < 8; ++j)
                    #pragma unroll
                    for (int w = 0; w < 4; ++w)
                        d[j][w] = ld64(p0 + (size_t)(b * 8 + j) * 16 + w);
                unsigned bad = 0;
                #pragma unroll
                for (int j = 0; j < 8; ++j)
                    #pragma unroll
                    for (int w = 0; w < 4; ++w) {
                        ull x = d[j][w];
                        bad |= (((unsigned)(x >> 16) & 0xFFFFu) ^ want)
                             | ((unsigned)(x >> 48) ^ want);
                    }
                if (__ballot(bad != 0) == 0ull) {
                    #pragma unroll
                    for (int j = 0; j < 8; ++j) {
                        short8 s;
                        #pragma unroll
                        for (int w = 0; w < 4; ++w) {
                            s[2 * w]     = (short)(unsigned short)(d[j][w] & 0xFFFFu);
                            s[2 * w + 1] = (short)(unsigned short)((d[j][w] >> 32) & 0xFFFFu);
                        }
                        frag[b * 8 + j] = s;
                    }
                    break;
                }
            }
        }
        __builtin_amdgcn_sched_barrier(0);
    };

    // epilogue: lane l and l^8 hold {i,f} / {g,o} swapped for same hcol
    auto epilogue = [&](f32x4 acc0, f32x4 acc1, float* cst,
                        float bi, float bf_, float bgt, float bo,
                        unsigned* tslot, unsigned tag, bool wlast) {
        f32x4 s0, s1;
        #pragma unroll
        for (int i = 0; i < 4; ++i) {
            s0[i] = __shfl_xor(acc0[i], 8, 64);
            s1[i] = __shfl_xor(acc1[i], 8, 64);
        }
        const bool lower = (c16 < 8);
        unsigned* tw = tslot + (size_t)(bg * 16 + kg * 4) * NH + ct * 8 + hc8;
        #pragma unroll
        for (int i = 0; i < 4; ++i) {
            float gi = (lower ? acc0[i] : s0[i]) + bi;
            float gf = (lower ? s0[i] : acc0[i]) + bf_;
            float gg = (lower ? acc1[i] : s1[i]) + bgt;
            float go = (lower ? s1[i] : acc1[i]) + bo;
            float c_ = sigm(gf) * cst[i] + sigm(gi) * tanh_(gg);
            cst[i] = c_;
            float hv = sigm(go) * tanh_(c_);
            if (lower) {
                __hip_atomic_store(tw + (size_t)i * NH,
                                   (tag << 16) | (unsigned)f2bf(hv),
                                   __ATOMIC_RELAXED, __HIP_MEMORY_SCOPE_AGENT);
                if (wlast)
                    hlast[(bg * 16 + kg * 4 + i) * NH + ct * 8 + hc8] = hv;
            }
        }
    };

    short8 hfrag[16];   // h0[r-1] values: L0 h-part AND L1 x-part; reused for th1

    for (int r = 0; r <= NS; ++r) {
        f32x4 a0 = {0.f, 0.f, 0.f, 0.f};
        f32x4 a1 = {0.f, 0.f, 0.f, 0.f};
        // ---- L0 x-part first (independent of recurrence)
        if (r < NS) {
            const unsigned short* xp = xbf + (aseq + r) * NF + kg * 8;
            #pragma unroll
            for (int ks = 0; ks < 4; ++ks) {
                short8 a = *(const short8*)(xp + ks * 32);
                int boff = 1024 + ks * 64 + kg * 16;
                a0 = __builtin_amdgcn_mfma_f32_16x16x32_bf16(a, *(const short8*)(lA0 + (boff ^ swz)), a0, 0, 0, 0);
                a1 = __builtin_amdgcn_mfma_f32_16x16x32_bf16(a, *(const short8*)(lB0 + (boff ^ swz)), a1, 0, 0, 0);
            }
        }
        // ---- acquire h0[r-1] (tagged poll; tag = r)
        if (r > 0) poll_tensor(th0 + ((size_t)((r - 1) & 1)) * TH_SLOT, (unsigned)r, hfrag);
        // ---- L0 h-part + epilogue: produces h0[r], tag r+1
        if (r < NS) {
            if (r > 0) {
                #pragma unroll
                for (int ks = 0; ks < 16; ++ks) {
                    int boff = ks * 64 + kg * 16;
                    a0 = __builtin_amdgcn_mfma_f32_16x16x32_bf16(hfrag[ks], *(const short8*)(lA0 + (boff ^ swz)), a0, 0, 0, 0);
                    a1 = __builtin_amdgcn_mfma_f32_16x16x32_bf16(hfrag[ks], *(const short8*)(lB0 + (boff ^ swz)), a1, 0, 0, 0);
                }
            }
            epilogue(a0, a1, cst0, bi0, bf0, bg0, bo0,
                     th0 + ((size_t)(r & 1)) * TH_SLOT, (unsigned)(r + 1), false);
        }
        // ---- L1 half: step t1 = r-1; x-part (hfrag, in-reg) hides th1 poll
        if (r > 0) {
            int t1 = r - 1;
            f32x4 c0 = {0.f, 0.f, 0.f, 0.f};
            f32x4 c1 = {0.f, 0.f, 0.f, 0.f};
            #pragma unroll
            for (int ks = 0; ks < 16; ++ks) {
                int boff = 1024 + ks * 64 + kg * 16;
                c0 = __builtin_amdgcn_mfma_f32_16x16x32_bf16(hfrag[ks], *(const short8*)(lA1 + (boff ^ swz)), c0, 0, 0, 0);
                c1 = __builtin_amdgcn_mfma_f32_16x16x32_bf16(hfrag[ks], *(const short8*)(lB1 + (boff ^ swz)), c1, 0, 0, 0);
            }
            if (t1 > 0) {
                poll_tensor(th1 + ((size_t)(r & 1)) * TH_SLOT, (unsigned)t1, hfrag);
                #pragma unroll
                for (int ks = 0; ks < 16; ++ks) {
                    int boff = ks * 64 + kg * 16;
                    c0 = __builtin_amdgcn_mfma_f32_16x16x32_bf16(hfrag[ks], *(const short8*)(lA1 + (boff ^ swz)), c0, 0, 0, 0);
                    c1 = __builtin_amdgcn_mfma_f32_16x16x32_bf16(hfrag[ks], *(const short8*)(lB1 + (boff ^ swz)), c1, 0, 0, 0);
                }
            }
            epilogue(c0, c1, cst1, bi1, bf1, bg1, bo1,
                     th1 + ((size_t)(t1 & 1)) * TH_SLOT, (unsigned)(t1 + 1), t1 == NS - 1);
        }
    }
}

// one block per batch row; mode 1 = relu, 2 = sigmoid
__global__ void dense(const float* __restrict__ in, const float* __restrict__ W,
                      const float* __restrict__ bias, float* __restrict__ out,
                      int K, int N, int mode) {
    int b = blockIdx.x;
    int j = threadIdx.x;
    extern __shared__ float srow[];
    for (int k = j; k < K; k += blockDim.x) srow[k] = in[b * K + k];
    __syncthreads();
    if (j < N) {
        float acc = bias[j];
        for (int k = 0; k < K; ++k) acc += srow[k] * W[k * N + j];
        if (mode == 1) acc = fmaxf(acc, 0.0f);
        else           acc = 1.0f / (1.0f + __expf(-acc));
        out[b * N + j] = acc;
    }
}

extern "C" void kernel_launch(void* const* d_in, const int* in_sizes, int n_in,
                              void* d_out, int out_size, void* d_ws, size_t ws_size,
                              hipStream_t stream) {
    const float* x    = (const float*)d_in[0];
    const float* Wx0  = (const float*)d_in[1];
    const float* Wh0  = (const float*)d_in[2];
    const float* b0   = (const float*)d_in[3];
    const float* Wx1  = (const float*)d_in[4];
    const float* Wh1  = (const float*)d_in[5];
    const float* b1   = (const float*)d_in[6];
    const float* Wd0  = (const float*)d_in[7];
    const float* bd0  = (const float*)d_in[8];
    const float* Wd1  = (const float*)d_in[9];
    const float* bd1  = (const float*)d_in[10];
    const float* Wout = (const float*)d_in[11];
    const float* bout = (const float*)d_in[12];

    char* ws = (char*)d_ws;
    size_t off = 0;
    auto alloc = [&](size_t bytes) { void* p = ws + off; off += (bytes + 255) & ~255ull; return p; };
    unsigned* th0 = (unsigned*)alloc((size_t)2 * TH_SLOT * 4);
    unsigned* th1 = (unsigned*)alloc((size_t)2 * TH_SLOT * 4);
    unsigned short* xbf  = (unsigned short*)alloc((size_t)NB * NS * NF * 2);
    unsigned short* whT0 = (unsigned short*)alloc((size_t)NG * NH * 2);
    unsigned short* wxT0 = (unsigned short*)alloc((size_t)NG * NF * 2);
    unsigned short* whT1 = (unsigned short*)alloc((size_t)NG * NH * 2);
    unsigned short* wxT1 = (unsigned short*)alloc((size_t)NG * NH * 2);
    float* hlast = (float*)alloc((size_t)NB * NH * 4);
    float* dt0   = (float*)alloc((size_t)NB * 512 * 4);
    float* dt1   = (float*)alloc((size_t)NB * 256 * 4);

    // zero tags EVERY launch: stale tags from a previous replay must never
    // satisfy a poll (th0 and th1 are contiguous: one memset covers both).
    hipMemsetAsync(th0, 0, (size_t)4 * TH_SLOT * 4, stream);
    cvt_bf16<<<2048, 256, 0, stream>>>(x, xbf, NB * NS * NF);
    tr_cvt<<<(NG * NF + 255) / 256, 256, 0, stream>>>(Wx0, wxT0, NF, NG);
    tr_cvt<<<(NG * NH + 255) / 256, 256, 0, stream>>>(Wh0, whT0, NH, NG);
    tr_cvt<<<(NG * NH + 255) / 256, 256, 0, stream>>>(Wx1, wxT1, NH, NG);
    tr_cvt<<<(NG * NH + 255) / 256, 256, 0, stream>>>(Wh1, whT1, NH, NG);

    void* args[] = { (void*)&xbf, (void*)&th0, (void*)&th1,
                     (void*)&whT0, (void*)&wxT0, (void*)&whT1, (void*)&wxT1,
                     (void*)&b0, (void*)&b1, (void*)&hlast };
    hipLaunchCooperativeKernel((void*)lstm_coop, dim3(NBLK), dim3(64), args, 0, stream);

    dense<<<NB, 512, 512 * 4, stream>>>(hlast, Wd0, bd0, dt0, 512, 512, 1);
    dense<<<NB, 256, 512 * 4, stream>>>(dt0, Wd1, bd1, dt1, 512, 256, 1);
    dense<<<NB, 128, 256 * 4, stream>>>(dt1, Wout, bout, (float*)d_out, 256, 96, 2);
}